// Round 10
// baseline (335.268 us; speedup 1.0000x reference)
//
#include <hip/hip_runtime.h>
#include <hip/hip_bf16.h>
#include <cstdint>

// LSTM cell: B=8192, D=1024, U=1024.
// z = [X|H](8192x2048) @ Wcat(2048x4096), gate interleave 16 in N, fused epilogue.
// GEMM: 256x256 tile, BK=32, 8 waves (2Mx4N), 512 thr.
// A: DIRECT global->register (no LDS; zero intra-block reuse), p/q double-buffered,
//    prefetched 1 window ahead. B: LDS (2x wm reuse), 3 bufs x 16KB, staged 2 ahead.
// One vmcnt(2) + one barrier per window; compiler-scheduled lgkm waits.

using f32x4  = __attribute__((ext_vector_type(4))) float;
using short8 = __attribute__((ext_vector_type(8))) short;

__device__ __forceinline__ unsigned short f2bf(float f) {
  union { float f; unsigned int u; } v; v.f = f;
  unsigned int r = v.u + 0x7fffu + ((v.u >> 16) & 1u);  // RNE
  return (unsigned short)(r >> 16);
}
__device__ __forceinline__ float sigmoidf_fast(float x) { return 1.f / (1.f + __expf(-x)); }
__device__ __forceinline__ float tanhf_fast(float x)    { return 1.f - 2.f / (__expf(2.f * x) + 1.f); }

// ---------- A conversion: Abf[b][k] = bf16(k<1024 ? X[b][k] : H[b][k-1024])
__global__ void conv_a_kernel(const float* __restrict__ X, const float* __restrict__ H,
                              unsigned short* __restrict__ Abf) {
  int idx = blockIdx.x * blockDim.x + threadIdx.x;
  int b  = idx >> 8;
  int kq = (idx & 255) << 2;
  float4 x = *(const float4*)(X + (long)b * 1024 + kq);
  float4 h = *(const float4*)(H + (long)b * 1024 + kq);
  ushort4 xo, ho;
  xo.x = f2bf(x.x); xo.y = f2bf(x.y); xo.z = f2bf(x.z); xo.w = f2bf(x.w);
  ho.x = f2bf(h.x); ho.y = f2bf(h.y); ho.z = f2bf(h.z); ho.w = f2bf(h.w);
  *(ushort4*)(Abf + (long)b * 2048 + kq)        = xo;
  *(ushort4*)(Abf + (long)b * 2048 + 1024 + kq) = ho;
}

// ---------- B conversion: Bt[n][k] bf16, N-major, n = (u>>4)*64 + g*16 + (u&15)
__global__ void conv_b_kernel(const float* W_i, const float* U_i,
                              const float* W_f, const float* U_f,
                              const float* W_c, const float* U_c,
                              const float* W_o, const float* U_o,
                              unsigned short* __restrict__ Bt) {
  __shared__ float tile[64][65];
  int z = blockIdx.z;
  const float* src;
  switch (z) {
    case 0: src = W_i; break; case 1: src = U_i; break;
    case 2: src = W_f; break; case 3: src = U_f; break;
    case 4: src = W_c; break; case 5: src = U_c; break;
    case 6: src = W_o; break; default: src = U_o; break;
  }
  int g = z >> 1, s = z & 1;
  int k0 = blockIdx.x * 64;
  int u0 = blockIdx.y * 64;
  int t = threadIdx.x;
  int c = t & 63, r0 = t >> 6;
#pragma unroll
  for (int i = 0; i < 16; ++i) {
    int r = i * 4 + r0;
    tile[r][c] = src[(long)(k0 + r) * 1024 + u0 + c];
  }
  __syncthreads();
  int ul = t >> 2;
  int ks = (t & 3) * 16;
  unsigned short outv[16];
#pragma unroll
  for (int j = 0; j < 16; ++j) outv[j] = f2bf(tile[ks + j][ul]);
  long n   = 4L * u0 + (ul >> 4) * 64 + g * 16 + (ul & 15);
  long col = (long)s * 1024 + k0 + ks;
  uint4* dst = (uint4*)(Bt + n * 2048 + col);
  dst[0] = *(uint4*)(outv);
  dst[1] = *(uint4*)(outv + 8);
}

// ---------- fused GEMM + LSTM epilogue
__global__ __launch_bounds__(512, 2) void lstm_gemm_kernel(
    const unsigned short* __restrict__ Abf,   // [8192][2048] bf16
    const unsigned short* __restrict__ Btbf,  // [4096][2048] bf16 (N-major)
    const float* __restrict__ b_i, const float* __restrict__ b_f,
    const float* __restrict__ b_c, const float* __restrict__ b_o,
    const float* __restrict__ c_tm1,
    float* __restrict__ outH, float* __restrict__ outC) {
  __shared__ unsigned short smem[3 * 8192];   // 3 B-buffers x 16KB = 48KB

  int bid = blockIdx.x;
  int swz = (bid & 7) * 64 + (bid >> 3);  // XCD swizzle, 512 % 8 == 0
  int bm = swz >> 4;   // 32 m-blocks
  int bn = swz & 15;   // 16 n-blocks

  int t = threadIdx.x;
  int lane = t & 63;
  int w = t >> 6;           // 8 waves
  int wm = w >> 2;          // 0..1
  int wn = w & 3;           // 0..3
  int rl = lane & 15;
  int kg = lane >> 4;       // 0..3, 8-elem k-chunk

  // ---- B ds_read frag offsets within a 8192-elem buf (XOR chunk swizzle) ----
#define BOFFE(NI) ((wn * 64 + (NI) * 16 + rl) * 32 + \
    ((kg ^ (((wn * 64 + (NI) * 16 + rl) >> 1) & 3)) << 3))
  const int offB0 = BOFFE(0), offB1 = BOFFE(1), offB2 = BOFFE(2), offB3 = BOFFE(3);
#undef BOFFE

  // ---- A direct per-lane base: A[bm*256 + wm*128 + rl][kg*8]; frag mi at +mi*32768 ----
  const unsigned short* gA = Abf + (long)(bm * 256 + wm * 128 + rl) * 2048 + kg * 8;

  // ---- B staging: linear LDS dest, inverse-swizzled global source ----
  int srow = t >> 2;                                  // 0..127 (+128 second GLL)
  int cbe  = (((t & 3) ^ ((srow >> 1) & 3))) << 3;    // source k-elem offset
  const unsigned short* bS0 = Btbf + (long)(bn * 256 + srow) * 2048 + cbe;
  const unsigned short* bS1 = bS0 + 128L * 2048;
  const int dB = t * 8;

#define GLL(SRC, DELM)                                                                     \
  __builtin_amdgcn_global_load_lds((const __attribute__((address_space(1))) void*)(SRC),   \
      (__attribute__((address_space(3))) void*)(&smem[DELM]), 16, 0, 0)
#define GLLB(SB, KOFF)                                                         \
  do {                                                                         \
    GLL(bS0 + (KOFF), (SB) * 8192 + dB);                                       \
    GLL(bS1 + (KOFF), (SB) * 8192 + 4096 + dB);                                \
  } while (0)
#define VMC(N) asm volatile("s_waitcnt vmcnt(" #N ")" ::: "memory")

  f32x4 acc[8][4];
#pragma unroll
  for (int mi = 0; mi < 8; ++mi)
#pragma unroll
    for (int ni = 0; ni < 4; ++ni) acc[mi][ni] = (f32x4){0.f, 0.f, 0.f, 0.f};

  // A fragment regsets p/q (8 frags each), B frags bb0-3
  short8 pa0, pa1, pa2, pa3, pa4, pa5, pa6, pa7;
  short8 qa0, qa1, qa2, qa3, qa4, qa5, qa6, qa7;
  short8 bb0, bb1, bb2, bb3;

#define LOADA(S, KO)                                                           \
  do {                                                                         \
    S##a0 = *(const short8*)(gA + 0 * 32768 + (KO));                           \
    S##a1 = *(const short8*)(gA + 1 * 32768 + (KO));                           \
    S##a2 = *(const short8*)(gA + 2 * 32768 + (KO));                           \
    S##a3 = *(const short8*)(gA + 3 * 32768 + (KO));                           \
    S##a4 = *(const short8*)(gA + 4 * 32768 + (KO));                           \
    S##a5 = *(const short8*)(gA + 5 * 32768 + (KO));                           \
    S##a6 = *(const short8*)(gA + 6 * 32768 + (KO));                           \
    S##a7 = *(const short8*)(gA + 7 * 32768 + (KO));                           \
  } while (0)

#define MF4(AF, MI)                                                                      \
  acc[MI][0] = __builtin_amdgcn_mfma_f32_16x16x32_bf16(AF, bb0, acc[MI][0], 0, 0, 0);    \
  acc[MI][1] = __builtin_amdgcn_mfma_f32_16x16x32_bf16(AF, bb1, acc[MI][1], 0, 0, 0);    \
  acc[MI][2] = __builtin_amdgcn_mfma_f32_16x16x32_bf16(AF, bb2, acc[MI][2], 0, 0, 0);    \
  acc[MI][3] = __builtin_amdgcn_mfma_f32_16x16x32_bf16(AF, bb3, acc[MI][3], 0, 0, 0);

// Window kt: A-frags of kt in regset C (loaded during kt-1); loads A(kt+1) into N;
// reads B(kt) from buf RB; stages B(kt+2) into buf SB; vmcnt(2)+barrier at end.
#define WINDOW(RB, SB, KOA, KOB, C, N, DOA, DOST, VMN, DOBAR)                  \
  {                                                                            \
    if (DOA) LOADA(N, KOA);                                                    \
    const unsigned short* Bb_ = smem + (RB) * 8192;                            \
    bb0 = *(const short8*)(Bb_ + offB0);                                       \
    bb1 = *(const short8*)(Bb_ + offB1);                                       \
    bb2 = *(const short8*)(Bb_ + offB2);                                       \
    bb3 = *(const short8*)(Bb_ + offB3);                                       \
    if (DOST) GLLB(SB, KOB);                                                   \
    __builtin_amdgcn_s_setprio(1);                                             \
    MF4(C##a0, 0) MF4(C##a1, 1) MF4(C##a2, 2) MF4(C##a3, 3)                    \
    MF4(C##a4, 4) MF4(C##a5, 5) MF4(C##a6, 6) MF4(C##a7, 7)                    \
    __builtin_amdgcn_s_setprio(0);                                             \
    if ((VMN) == 2) VMC(2);                                                    \
    if ((VMN) == 0) VMC(0);                                                    \
    if (DOBAR) __builtin_amdgcn_s_barrier();                                   \
  }

  // ---- prologue: stage B0->buf0, B1->buf1; load A(0)->p; wait B0 ----
  GLLB(0, 0);
  GLLB(1, 32);
  LOADA(p, 0);
  VMC(10);   // B0's 2 GLLs done (oldest); A loads tracked too, counted from newest
  __builtin_amdgcn_s_barrier();

  // ---- windows 0..59: 10 groups of 6 (regset period 2, buf period 3) ----
  for (int g = 0; g < 10; ++g) {
    WINDOW(0, 2, 32,  64,  p, q, 1, 1, 2, 1);
    WINDOW(1, 0, 64,  96,  q, p, 1, 1, 2, 1);
    WINDOW(2, 1, 96,  128, p, q, 1, 1, 2, 1);
    WINDOW(0, 2, 128, 160, q, p, 1, 1, 2, 1);
    WINDOW(1, 0, 160, 192, p, q, 1, 1, 2, 1);
    WINDOW(2, 1, 192, 224, q, p, 1, 1, 2, 1);
    gA += 192; bS0 += 192; bS1 += 192;
  }
  // ---- tail: kt=60 (stage B62), 61 (stage B63), 62 (drain), 63 (pure) ----
  WINDOW(0, 2, 32, 64, p, q, 1, 1, 2, 1);
  WINDOW(1, 0, 64, 96, q, p, 1, 1, 2, 1);
  WINDOW(2, 0, 96, 0,  p, q, 1, 0, 0, 1);
  WINDOW(0, 0, 0,  0,  q, p, 0, 0, -1, 0);
#undef WINDOW
#undef MF4
#undef LOADA
#undef VMC
#undef GLLB
#undef GLL

  // ---- fused LSTM epilogue ----
  // Wave N-span = 64 cols = one u-block: u = nbase/4 + rl; gate = ni.
  int mbase = bm * 256 + wm * 128;
  int nbase = bn * 256 + wn * 64;
  int u = (nbase >> 2) + rl;
  float bi_v = b_i[u], bf_v = b_f[u], bc_v = b_c[u], bo_v = b_o[u];
  int rquad = (lane >> 4) << 2;
#pragma unroll
  for (int mi = 0; mi < 8; ++mi) {
#pragma unroll
    for (int j = 0; j < 4; ++j) {
      int brow = mbase + mi * 16 + rquad + j;
      float zi = acc[mi][0][j] + bi_v;
      float zf = acc[mi][1][j] + bf_v;
      float zc = acc[mi][2][j] + bc_v;
      float zo = acc[mi][3][j] + bo_v;
      float ig = sigmoidf_fast(zi);
      float fg = sigmoidf_fast(zf);
      float cg = tanhf_fast(zc);
      float og = sigmoidf_fast(zo);
      float cp = c_tm1[(long)brow * 1024 + u];
      float cn = fg * cp + ig * cg;
      float hn = og * tanhf_fast(cn);
      outH[(long)brow * 1024 + u] = hn;
      outC[(long)brow * 1024 + u] = cn;
    }
  }
}

extern "C" void kernel_launch(void* const* d_in, const int* in_sizes, int n_in,
                              void* d_out, int out_size, void* d_ws, size_t ws_size,
                              hipStream_t stream) {
  (void)in_sizes; (void)n_in; (void)out_size; (void)ws_size;
  const float* X   = (const float*)d_in[0];
  const float* Hst = (const float*)d_in[1];
  const float* Cst = (const float*)d_in[2];
  const float* W_i = (const float*)d_in[3];
  const float* U_i = (const float*)d_in[4];
  const float* b_i = (const float*)d_in[5];
  const float* W_f = (const float*)d_in[6];
  const float* U_f = (const float*)d_in[7];
  const float* b_f = (const float*)d_in[8];
  const float* W_c = (const float*)d_in[9];
  const float* U_c = (const float*)d_in[10];
  const float* b_c = (const float*)d_in[11];
  const float* W_o = (const float*)d_in[12];
  const float* U_o = (const float*)d_in[13];
  const float* b_o = (const float*)d_in[14];

  unsigned short* Abf  = (unsigned short*)d_ws;                        // 32 MB
  unsigned short* Btbf = (unsigned short*)((char*)d_ws + 33554432);    // 16 MB

  float* outH = (float*)d_out;
  float* outC = outH + 8192L * 1024;

  conv_a_kernel<<<8192, 256, 0, stream>>>(X, Hst, Abf);
  conv_b_kernel<<<dim3(16, 16, 8), 256, 0, stream>>>(W_i, U_i, W_f, U_f, W_c, U_c, W_o, U_o, Btbf);
  lstm_gemm_kernel<<<512, 512, 0, stream>>>(Abf, Btbf, b_i, b_f, b_c, b_o, Cst, outH, outC);
}

// Round 11
// 157.783 us; speedup vs baseline: 2.1249x; 2.1249x over previous
//
#include <hip/hip_runtime.h>
#include <hip/hip_bf16.h>
#include <cstdint>

// LSTM cell: B=8192, D=1024, U=1024.
// z = [X|H](8192x2048) @ Wcat(2048x4096), gate interleave 16 in N, fused epilogue.
// GEMM: m201-faithful 8-phase schedule. 256x256 tile, 8 waves (2Mx4N), 512 thr.
// Iteration = 2 K-tiles (BK=64 each), 8 phases; phase = one C-quadrant x K=64
// (16 MFMA). LDS 128KB: A[2 tile][2 Mhalf][2 kk][128r][32k] + B same. Derived
// waits: stage {ph1:A1(j), ph2/3:B0(j+1), ph5/6:A0(j+1), ph7/8:B1(j+1)},
// vmcnt(4) at ph4/ph8 only (4 loads always in flight). XOR chunk swizzle.

using f32x4  = __attribute__((ext_vector_type(4))) float;
using short8 = __attribute__((ext_vector_type(8))) short;

__device__ __forceinline__ unsigned short f2bf(float f) {
  union { float f; unsigned int u; } v; v.f = f;
  unsigned int r = v.u + 0x7fffu + ((v.u >> 16) & 1u);  // RNE
  return (unsigned short)(r >> 16);
}
__device__ __forceinline__ float sigmoidf_fast(float x) { return 1.f / (1.f + __expf(-x)); }
__device__ __forceinline__ float tanhf_fast(float x)    { return 1.f - 2.f / (__expf(2.f * x) + 1.f); }

// ---------- A conversion: Abf[b][k] = bf16(k<1024 ? X[b][k] : H[b][k-1024])
__global__ void conv_a_kernel(const float* __restrict__ X, const float* __restrict__ H,
                              unsigned short* __restrict__ Abf) {
  int idx = blockIdx.x * blockDim.x + threadIdx.x;
  int b  = idx >> 8;
  int kq = (idx & 255) << 2;
  float4 x = *(const float4*)(X + (long)b * 1024 + kq);
  float4 h = *(const float4*)(H + (long)b * 1024 + kq);
  ushort4 xo, ho;
  xo.x = f2bf(x.x); xo.y = f2bf(x.y); xo.z = f2bf(x.z); xo.w = f2bf(x.w);
  ho.x = f2bf(h.x); ho.y = f2bf(h.y); ho.z = f2bf(h.z); ho.w = f2bf(h.w);
  *(ushort4*)(Abf + (long)b * 2048 + kq)        = xo;
  *(ushort4*)(Abf + (long)b * 2048 + 1024 + kq) = ho;
}

// ---------- B conversion: Bt[n][k] bf16, N-major, n = (u>>4)*64 + g*16 + (u&15)
__global__ void conv_b_kernel(const float* W_i, const float* U_i,
                              const float* W_f, const float* U_f,
                              const float* W_c, const float* U_c,
                              const float* W_o, const float* U_o,
                              unsigned short* __restrict__ Bt) {
  __shared__ float tile[64][65];
  int z = blockIdx.z;
  const float* src;
  switch (z) {
    case 0: src = W_i; break; case 1: src = U_i; break;
    case 2: src = W_f; break; case 3: src = U_f; break;
    case 4: src = W_c; break; case 5: src = U_c; break;
    case 6: src = W_o; break; default: src = U_o; break;
  }
  int g = z >> 1, s = z & 1;
  int k0 = blockIdx.x * 64;
  int u0 = blockIdx.y * 64;
  int t = threadIdx.x;
  int c = t & 63, r0 = t >> 6;
#pragma unroll
  for (int i = 0; i < 16; ++i) {
    int r = i * 4 + r0;
    tile[r][c] = src[(long)(k0 + r) * 1024 + u0 + c];
  }
  __syncthreads();
  int ul = t >> 2;
  int ks = (t & 3) * 16;
  unsigned short outv[16];
#pragma unroll
  for (int j = 0; j < 16; ++j) outv[j] = f2bf(tile[ks + j][ul]);
  long n   = 4L * u0 + (ul >> 4) * 64 + g * 16 + (ul & 15);
  long col = (long)s * 1024 + k0 + ks;
  uint4* dst = (uint4*)(Bt + n * 2048 + col);
  dst[0] = *(uint4*)(outv);
  dst[1] = *(uint4*)(outv + 8);
}

// ---------- fused GEMM + LSTM epilogue
// LDS (shorts): A: D*16384 + H*8192 + KK*4096 + r*32 + c*8  (D=tile, H=Mhalf,
// KK=k-half, r in [0,128), swizzled chunk c). B: +32768, H=Nhalf. 128KB total.
__global__ __launch_bounds__(512, 2) void lstm_gemm_kernel(
    const unsigned short* __restrict__ Abf,   // [8192][2048] bf16
    const unsigned short* __restrict__ Btbf,  // [4096][2048] bf16 (N-major)
    const float* __restrict__ b_i, const float* __restrict__ b_f,
    const float* __restrict__ b_c, const float* __restrict__ b_o,
    const float* __restrict__ c_tm1,
    float* __restrict__ outH, float* __restrict__ outC) {
  __shared__ unsigned short smem[65536];  // 128KB

  int bid = blockIdx.x;
  int swz = (bid & 7) * 64 + (bid >> 3);  // XCD swizzle, 512 % 8 == 0
  int bm = swz >> 4;   // 32 m-blocks
  int bn = swz & 15;   // 16 n-blocks

  int t = threadIdx.x;
  int lane = t & 63;
  int w = t >> 6;           // 8 waves
  int wm = w >> 2;          // 0..1
  int wn = w & 3;           // 0..3
  int rl = lane & 15;
  int kg = lane >> 4;       // 0..3, 8-elem k-chunk

  // ---- ds_read fragment offsets (XOR chunk swizzle c ^= (row>>1)&3) ----
#define ADEF(MI)                                                               \
  const int offA_##MI##_0 = wm * 8192 + ((MI) * 16 + rl) * 32 +                \
      ((kg ^ ((((MI) * 16 + rl) >> 1) & 3)) << 3);                             \
  const int offA_##MI##_1 = offA_##MI##_0 + 4096;
  ADEF(0) ADEF(1) ADEF(2) ADEF(3) ADEF(4) ADEF(5) ADEF(6) ADEF(7)
#undef ADEF
#define BDEF(NI)                                                               \
  const int offB_##NI##_0 = 32768 + ((wn * 64 + (NI) * 16 + rl) >> 7) * 8192 + \
      ((wn * 64 + (NI) * 16 + rl) & 127) * 32 +                                \
      ((kg ^ (((wn * 64 + (NI) * 16 + rl) >> 1) & 3)) << 3);                   \
  const int offB_##NI##_1 = offB_##NI##_0 + 4096;
  BDEF(0) BDEF(1) BDEF(2) BDEF(3)
#undef BDEF

  // ---- staging: linear LDS dest, inverse-swizzled global source ----
  int srow = t >> 2;                                  // 0..127
  int cbe  = ((t & 3) ^ ((srow >> 1) & 3)) << 3;      // source chunk (involution)
  const unsigned short* aSrc = Abf  + (long)(bm * 256 + srow) * 2048 + cbe;
  const unsigned short* bSrc = Btbf + (long)(bn * 256 + srow) * 2048 + cbe;
  const int dA = t * 8;

#define GLL(SRC, DELM)                                                                     \
  __builtin_amdgcn_global_load_lds((const __attribute__((address_space(1))) void*)(SRC),   \
      (__attribute__((address_space(3))) void*)(&smem[DELM]), 16, 0, 0)
  // stage one half-tile (2 GLLs: KK=0 then KK=1). KE = k-element offset of tile.
#define STA(D, H, KE)                                                          \
  do {                                                                         \
    GLL(aSrc + (H) * 262144 + (KE),      (D) * 16384 + (H) * 8192 + dA);       \
    GLL(aSrc + (H) * 262144 + (KE) + 32, (D) * 16384 + (H) * 8192 + 4096 + dA);\
  } while (0)
#define STB(D, H, KE)                                                          \
  do {                                                                         \
    GLL(bSrc + (H) * 262144 + (KE),      32768 + (D) * 16384 + (H) * 8192 + dA);\
    GLL(bSrc + (H) * 262144 + (KE) + 32, 32768 + (D) * 16384 + (H) * 8192 + 4096 + dA);\
  } while (0)
#define VMC(N)  asm volatile("s_waitcnt vmcnt(" #N ")" ::: "memory")
#define LGK(N)  asm volatile("s_waitcnt lgkmcnt(" #N ")" ::: "memory")
#define BAR()   __builtin_amdgcn_s_barrier()
#define SB0()   __builtin_amdgcn_sched_barrier(0)
#define PRIO(P) __builtin_amdgcn_s_setprio(P)

  f32x4 acc[8][4];
#pragma unroll
  for (int mi = 0; mi < 8; ++mi)
#pragma unroll
    for (int ni = 0; ni < 4; ++ni) acc[mi][ni] = (f32x4){0.f, 0.f, 0.f, 0.f};

  short8 aw00, aw01, aw10, aw11;                       // A frags: (M0,kk0/1),(M1,kk0/1)
  short8 bb00, bb01, bb02, bb03, bb10, bb11, bb12, bb13;  // B frags: kk x ni

#define BRD(D)                                                                 \
  { const unsigned short* S_ = smem + (D) * 16384;                             \
    bb00 = *(const short8*)(S_ + offB_0_0);                                    \
    bb01 = *(const short8*)(S_ + offB_1_0);                                    \
    bb02 = *(const short8*)(S_ + offB_2_0);                                    \
    bb03 = *(const short8*)(S_ + offB_3_0);                                    \
    bb10 = *(const short8*)(S_ + offB_0_1);                                    \
    bb11 = *(const short8*)(S_ + offB_1_1);                                    \
    bb12 = *(const short8*)(S_ + offB_2_1);                                    \
    bb13 = *(const short8*)(S_ + offB_3_1); }
#define ARD(D, M0, M1)                                                         \
  { const unsigned short* S_ = smem + (D) * 16384;                             \
    aw00 = *(const short8*)(S_ + offA_##M0##_0);                               \
    aw01 = *(const short8*)(S_ + offA_##M0##_1);                               \
    aw10 = *(const short8*)(S_ + offA_##M1##_0);                               \
    aw11 = *(const short8*)(S_ + offA_##M1##_1); }

#define MFMA1(A, B, C) __builtin_amdgcn_mfma_f32_16x16x32_bf16(A, B, C, 0, 0, 0)
#define MFQ(M0, M1)                                                            \
  acc[M0][0] = MFMA1(aw00, bb00, acc[M0][0]);                                  \
  acc[M0][1] = MFMA1(aw00, bb01, acc[M0][1]);                                  \
  acc[M0][2] = MFMA1(aw00, bb02, acc[M0][2]);                                  \
  acc[M0][3] = MFMA1(aw00, bb03, acc[M0][3]);                                  \
  acc[M1][0] = MFMA1(aw10, bb00, acc[M1][0]);                                  \
  acc[M1][1] = MFMA1(aw10, bb01, acc[M1][1]);                                  \
  acc[M1][2] = MFMA1(aw10, bb02, acc[M1][2]);                                  \
  acc[M1][3] = MFMA1(aw10, bb03, acc[M1][3]);                                  \
  acc[M0][0] = MFMA1(aw01, bb10, acc[M0][0]);                                  \
  acc[M0][1] = MFMA1(aw01, bb11, acc[M0][1]);                                  \
  acc[M0][2] = MFMA1(aw01, bb12, acc[M0][2]);                                  \
  acc[M0][3] = MFMA1(aw01, bb13, acc[M0][3]);                                  \
  acc[M1][0] = MFMA1(aw11, bb10, acc[M1][0]);                                  \
  acc[M1][1] = MFMA1(aw11, bb11, acc[M1][1]);                                  \
  acc[M1][2] = MFMA1(aw11, bb12, acc[M1][2]);                                  \
  acc[M1][3] = MFMA1(aw11, bb13, acc[M1][3]);

  // ---- prologue: stage A0(0), B0(0), B1(0); drain A0,B0; B1 stays in flight ----
  STA(0, 0, 0); STA(0, 1, 0);
  STB(0, 0, 0); STB(0, 1, 0);
  STB(1, 0, 64); STB(1, 1, 64);
  VMC(4);
  BAR();

  for (int j = 0; j < 16; ++j) {
    int kj1 = j * 128 + 64;           // A1(j) source k
    int kn  = ((j + 1) & 15) * 128;   // pair j+1 base (wraps at end; harmless)
    // ph1: Q0 of K-tile D=0; read B(D0)+Aq0; stage A1(j) both halves
    BRD(0) ARD(0, 0, 1)
    STA(1, 0, kj1); STA(1, 1, kj1);
    LGK(8);
    BAR(); LGK(0); SB0();
    PRIO(1); MFQ(0, 1) PRIO(0);
    BAR();
    // ph2: Q1; stage B0h0(j+1)
    ARD(0, 2, 3)
    STB(0, 0, kn);
    BAR(); LGK(0); SB0();
    PRIO(1); MFQ(2, 3) PRIO(0);
    BAR();
    // ph3: Q2; stage B0h1(j+1)
    ARD(0, 4, 5)
    STB(0, 1, kn);
    BAR(); LGK(0); SB0();
    PRIO(1); MFQ(4, 5) PRIO(0);
    BAR();
    // ph4: Q3; no stage; vmcnt(4) drains B1(j)+A1(j) (needed ph5)
    ARD(0, 6, 7)
    BAR(); LGK(0); SB0();
    PRIO(1); MFQ(6, 7) PRIO(0);
    VMC(4);
    BAR(); SB0();
    // ph5: Q0 of K-tile D=1; read B(D1)+Aq0; stage A0h0(j+1)
    BRD(1) ARD(1, 0, 1)
    STA(0, 0, kn);
    LGK(8);
    BAR(); LGK(0); SB0();
    PRIO(1); MFQ(0, 1) PRIO(0);
    BAR();
    // ph6: Q1; stage A0h1(j+1)
    ARD(1, 2, 3)
    STA(0, 1, kn);
    BAR(); LGK(0); SB0();
    PRIO(1); MFQ(2, 3) PRIO(0);
    BAR();
    // ph7: Q2; stage B1h0(j+1)
    ARD(1, 4, 5)
    STB(1, 0, kn + 64);
    BAR(); LGK(0); SB0();
    PRIO(1); MFQ(4, 5) PRIO(0);
    BAR();
    // ph8: Q3; stage B1h1(j+1); vmcnt(4) drains B0(j+1)+A0(j+1) (needed ph1')
    ARD(1, 6, 7)
    STB(1, 1, kn + 64);
    BAR(); LGK(0); SB0();
    PRIO(1); MFQ(6, 7) PRIO(0);
    VMC(4);
    BAR(); SB0();
  }
#undef MFQ
#undef MFMA1
#undef ARD
#undef BRD
#undef PRIO
#undef SB0
#undef BAR
#undef LGK
#undef VMC
#undef STB
#undef STA
#undef GLL

  // ---- fused LSTM epilogue ----
  // Wave N-span = 64 cols = one u-block: u = nbase/4 + rl; gate = ni.
  int mbase = bm * 256 + wm * 128;
  int nbase = bn * 256 + wn * 64;
  int u = (nbase >> 2) + rl;
  float bi_v = b_i[u], bf_v = b_f[u], bc_v = b_c[u], bo_v = b_o[u];
  int rquad = (lane >> 4) << 2;
#pragma unroll
  for (int mi = 0; mi < 8; ++mi) {
#pragma unroll
    for (int j = 0; j < 4; ++j) {
      int brow = mbase + mi * 16 + rquad + j;
      float zi = acc[mi][0][j] + bi_v;
      float zf = acc[mi][1][j] + bf_v;
      float zc = acc[mi][2][j] + bc_v;
      float zo = acc[mi][3][j] + bo_v;
      float ig = sigmoidf_fast(zi);
      float fg = sigmoidf_fast(zf);
      float cg = tanhf_fast(zc);
      float og = sigmoidf_fast(zo);
      float cp = c_tm1[(long)brow * 1024 + u];
      float cn = fg * cp + ig * cg;
      float hn = og * tanhf_fast(cn);
      outH[(long)brow * 1024 + u] = hn;
      outC[(long)brow * 1024 + u] = cn;
    }
  }
}

extern "C" void kernel_launch(void* const* d_in, const int* in_sizes, int n_in,
                              void* d_out, int out_size, void* d_ws, size_t ws_size,
                              hipStream_t stream) {
  (void)in_sizes; (void)n_in; (void)out_size; (void)ws_size;
  const float* X   = (const float*)d_in[0];
  const float* Hst = (const float*)d_in[1];
  const float* Cst = (const float*)d_in[2];
  const float* W_i = (const float*)d_in[3];
  const float* U_i = (const float*)d_in[4];
  const float* b_i = (const float*)d_in[5];
  const float* W_f = (const float*)d_in[6];
  const float* U_f = (const float*)d_in[7];
  const float* b_f = (const float*)d_in[8];
  const float* W_c = (const float*)d_in[9];
  const float* U_c = (const float*)d_in[10];
  const float* b_c = (const float*)d_in[11];
  const float* W_o = (const float*)d_in[12];
  const float* U_o = (const float*)d_in[13];
  const float* b_o = (const float*)d_in[14];

  unsigned short* Abf  = (unsigned short*)d_ws;                        // 32 MB
  unsigned short* Btbf = (unsigned short*)((char*)d_ws + 33554432);    // 16 MB

  float* outH = (float*)d_out;
  float* outC = outH + 8192L * 1024;

  conv_a_kernel<<<8192, 256, 0, stream>>>(X, Hst, Abf);
  conv_b_kernel<<<dim3(16, 16, 8), 256, 0, stream>>>(W_i, U_i, W_f, U_f, W_c, U_c, W_o, U_o, Btbf);
  lstm_gemm_kernel<<<512, 512, 0, stream>>>(Abf, Btbf, b_i, b_f, b_c, b_o, Cst, outH, outC);
}